// Round 1
// baseline (558.884 us; speedup 1.0000x reference)
//
#include <hip/hip_runtime.h>
#include <math.h>

// Problem constants
#define SS    256      // seq len
#define BB    4        // batch
#define HH    160      // hidden
#define NH_   8        // heads
#define HD_   20       // head dim
#define TBL   1025     // 2*MAXLEN+1
#define MAXL  512
#define FF_   640

// ---------------------------------------------------------------------------
// Kernel 1: P tables.  P[tab][row][c] = sum_cp pe_tab[row,cp] * W_fus[tab*H+cp, c]
// b_fus folded into tab 0.
// grid (1025, 4), block 160
// ---------------------------------------------------------------------------
__global__ __launch_bounds__(160) void k_ptab(
    const float* __restrict__ pe_ss, const float* __restrict__ pe_se,
    const float* __restrict__ pe_es, const float* __restrict__ pe_ee,
    const float* __restrict__ W_fus, const float* __restrict__ b_fus,
    float* __restrict__ P) {
  int row = blockIdx.x, tab = blockIdx.y, c = threadIdx.x;
  const float* pe = (tab == 0) ? pe_ss : (tab == 1) ? pe_se : (tab == 2) ? pe_es : pe_ee;
  __shared__ float xs[HH];
  xs[c] = pe[row * HH + c];
  __syncthreads();
  float acc = (tab == 0) ? b_fus[c] : 0.0f;
  const float* wcol = W_fus + (size_t)tab * HH * HH + c;
  #pragma unroll 4
  for (int cp = 0; cp < HH; ++cp) acc = fmaf(xs[cp], wcol[cp * HH], acc);
  P[((size_t)tab * TBL + row) * HH + c] = acc;
}

// ---------------------------------------------------------------------------
// Kernel 2: per-token q,k,v projections + g matrix + gb.
//   q[t,c] = inp[t,:]·Wq[:,c] + bq[c]   (same k, v)
//   g[t,h,c] = sum_d (q[t,h*20+d] + vtab[h,d]) * Wr[c, h*20+d]
//   gb[t,h]  = sum_d (q[t,h*20+d] + vtab[h,d]) * br[h*20+d]
// 8 tokens per block, 256 threads, grid 128
// ---------------------------------------------------------------------------
__global__ __launch_bounds__(256) void k_qkvg(
    const float* __restrict__ inp,
    const float* __restrict__ Wq, const float* __restrict__ bq,
    const float* __restrict__ Wk, const float* __restrict__ bk,
    const float* __restrict__ Wv, const float* __restrict__ bv,
    const float* __restrict__ Wr, const float* __restrict__ br,
    const float* __restrict__ vtab,
    float* __restrict__ qb, float* __restrict__ kb, float* __restrict__ vb,
    float* __restrict__ gmat, float* __restrict__ gbb) {
  const int T = 8;
  int tok0 = blockIdx.x * T;
  int t = threadIdx.x;
  __shared__ float xs[T][HH];
  __shared__ float qs[T][HH];
  for (int idx = t; idx < T * HH; idx += 256)
    xs[idx / HH][idx % HH] = inp[(size_t)tok0 * HH + idx];
  __syncthreads();
  // q,k,v: 8 tokens * 480 outputs
  for (int idx = t; idx < T * 480; idx += 256) {
    int tt = idx / 480, o = idx % 480;
    const float* W; const float* bias; int col;
    if (o < 160)      { W = Wq; bias = bq; col = o; }
    else if (o < 320) { W = Wk; bias = bk; col = o - 160; }
    else              { W = Wv; bias = bv; col = o - 320; }
    float acc = bias[col];
    #pragma unroll 4
    for (int cp = 0; cp < HH; ++cp) acc = fmaf(xs[tt][cp], W[cp * HH + col], acc);
    size_t gt = (size_t)(tok0 + tt) * HH + col;
    if (o < 160)      { qb[gt] = acc; qs[tt][col] = acc; }
    else if (o < 320) { kb[gt] = acc; }
    else              { vb[gt] = acc; }
  }
  __syncthreads();
  // g: 8 tokens * 8 heads * 160 c
  for (int idx = t; idx < T * NH_ * HH; idx += 256) {
    int tt = idx / (NH_ * HH);
    int rem = idx % (NH_ * HH);
    int h = rem / HH, c = rem % HH;
    float acc = 0.0f;
    #pragma unroll
    for (int d = 0; d < HD_; ++d)
      acc = fmaf(qs[tt][h * HD_ + d] + vtab[h * HD_ + d], Wr[(size_t)c * HH + h * HD_ + d], acc);
    gmat[(size_t)(tok0 + tt) * (NH_ * HH) + rem] = acc;
  }
  // gb: 8 tokens * 8 heads
  if (t < T * NH_) {
    int tt = t / NH_, h = t % NH_;
    float acc = 0.0f;
    #pragma unroll
    for (int d = 0; d < HD_; ++d)
      acc = fmaf(qs[tt][h * HD_ + d] + vtab[h * HD_ + d], br[h * HD_ + d], acc);
    gbb[(tok0 + tt) * NH_ + h] = acc;
  }
}

// ---------------------------------------------------------------------------
// Kernel 3: fused attention. One block per (b, i). 256 threads, thread = j.
//   rel[j,c] = relu(P_ss[dss]+P_se[dse]+P_es[des]+P_ee[dee])[c]   (bias folded)
//   B_D[h,j] = sum_c rel[j,c]*g[b,i,h,c] + gb[b,i,h]
//   A_C[h,j] = sum_d (q[b,i,h,d]+u[h,d]) * k[b,j,h,d]
//   score -> mask -> softmax over j -> out[h,d] = sum_j attn*val
// ---------------------------------------------------------------------------
__global__ __launch_bounds__(256) void k_attn(
    const float* __restrict__ qb, const float* __restrict__ kb, const float* __restrict__ vb,
    const float* __restrict__ gmat, const float* __restrict__ gbb,
    const float* __restrict__ P,
    const int* __restrict__ pos_s, const int* __restrict__ pos_e,
    const int* __restrict__ seq_len, const int* __restrict__ lex_num,
    const float* __restrict__ utab,
    float* __restrict__ attn_out) {
  int blk = blockIdx.x;        // b*S + i
  int b = blk >> 8;
  int i = blk & 255;
  int t = threadIdx.x;         // j
  __shared__ float qu[HH];
  __shared__ float g_s[NH_ * HH];
  __shared__ float gb_s[NH_];
  __shared__ float sc[NH_][SS];

  if (t < HH) qu[t] = qb[(size_t)blk * HH + t] + utab[t];
  for (int idx = t; idx < NH_ * HH; idx += 256) g_s[idx] = gmat[(size_t)blk * (NH_ * HH) + idx];
  if (t < NH_) gb_s[t] = gbb[blk * NH_ + t];
  __syncthreads();

  int j = t;
  int psi = pos_s[b * SS + i], pei = pos_e[b * SS + i];
  int psj = pos_s[b * SS + j], pej = pos_e[b * SS + j];
  const float* r0 = P + (size_t)(psi - psj + MAXL) * HH;
  const float* r1 = P + ((size_t)TBL + (psi - pej + MAXL)) * HH;
  const float* r2 = P + ((size_t)2 * TBL + (pei - psj + MAXL)) * HH;
  const float* r3 = P + ((size_t)3 * TBL + (pei - pej + MAXL)) * HH;

  float bd[NH_];
  #pragma unroll
  for (int h = 0; h < NH_; ++h) bd[h] = gb_s[h];

  #pragma unroll 2
  for (int cq = 0; cq < HH / 4; ++cq) {
    float4 a0 = *(const float4*)(r0 + cq * 4);
    float4 a1 = *(const float4*)(r1 + cq * 4);
    float4 a2 = *(const float4*)(r2 + cq * 4);
    float4 a3 = *(const float4*)(r3 + cq * 4);
    float rl0 = fmaxf(a0.x + a1.x + a2.x + a3.x, 0.0f);
    float rl1 = fmaxf(a0.y + a1.y + a2.y + a3.y, 0.0f);
    float rl2 = fmaxf(a0.z + a1.z + a2.z + a3.z, 0.0f);
    float rl3 = fmaxf(a0.w + a1.w + a2.w + a3.w, 0.0f);
    #pragma unroll
    for (int h = 0; h < NH_; ++h) {
      float4 gv = *(const float4*)(&g_s[h * HH + cq * 4]);
      bd[h] = fmaf(rl0, gv.x, bd[h]);
      bd[h] = fmaf(rl1, gv.y, bd[h]);
      bd[h] = fmaf(rl2, gv.z, bd[h]);
      bd[h] = fmaf(rl3, gv.w, bd[h]);
    }
  }

  // A_C
  float ac[NH_];
  const float* krow = kb + (size_t)(b * SS + j) * HH;
  #pragma unroll
  for (int h = 0; h < NH_; ++h) {
    const float4* k4 = (const float4*)(krow + h * HD_);
    const float4* q4 = (const float4*)(&qu[h * HD_]);
    float acc = 0.0f;
    #pragma unroll
    for (int d4 = 0; d4 < HD_ / 4; ++d4) {
      float4 kv = k4[d4]; float4 qv = q4[d4];
      acc = fmaf(qv.x, kv.x, acc);
      acc = fmaf(qv.y, kv.y, acc);
      acc = fmaf(qv.z, kv.z, acc);
      acc = fmaf(qv.w, kv.w, acc);
    }
    ac[h] = acc;
  }

  int limit = seq_len[b] + lex_num[0];
  const float scale = 0.22360679774997896f;  // 1/sqrt(20)
  bool valid = (j < limit);
  #pragma unroll
  for (int h = 0; h < NH_; ++h)
    sc[h][j] = valid ? (ac[h] + bd[h]) * scale : -1.0e15f;
  __syncthreads();

  // softmax: 8 groups of 32 lanes; group handles one head
  {
    int h = t >> 5, l = t & 31;
    float m = -3.0e38f;
    float e[8];
    #pragma unroll
    for (int ii = 0; ii < 8; ++ii) m = fmaxf(m, sc[h][l + ii * 32]);
    #pragma unroll
    for (int msk = 16; msk; msk >>= 1) m = fmaxf(m, __shfl_xor(m, msk));
    float s = 0.0f;
    #pragma unroll
    for (int ii = 0; ii < 8; ++ii) { e[ii] = __expf(sc[h][l + ii * 32] - m); s += e[ii]; }
    #pragma unroll
    for (int msk = 16; msk; msk >>= 1) s += __shfl_xor(s, msk);
    float inv = 1.0f / s;
    #pragma unroll
    for (int ii = 0; ii < 8; ++ii) sc[h][l + ii * 32] = e[ii] * inv;
  }
  __syncthreads();

  // PV: thread c<160 computes out[c]; h = c/20
  if (t < HH) {
    int h = t / HD_;
    float acc0 = 0.f, acc1 = 0.f, acc2 = 0.f, acc3 = 0.f;
    const float* vcol = vb + (size_t)b * SS * HH + t;
    #pragma unroll 2
    for (int j2 = 0; j2 < SS; j2 += 4) {
      acc0 = fmaf(sc[h][j2 + 0], vcol[(size_t)(j2 + 0) * HH], acc0);
      acc1 = fmaf(sc[h][j2 + 1], vcol[(size_t)(j2 + 1) * HH], acc1);
      acc2 = fmaf(sc[h][j2 + 2], vcol[(size_t)(j2 + 2) * HH], acc2);
      acc3 = fmaf(sc[h][j2 + 3], vcol[(size_t)(j2 + 3) * HH], acc3);
    }
    attn_out[(size_t)blk * HH + t] = (acc0 + acc1) + (acc2 + acc3);
  }
}

// ---------------------------------------------------------------------------
// LayerNorm helper: one wave normalizes 160 values in LDS (input already
// doubled: z = y + y), writes (z-mu)*rstd*g + b to out.
// ---------------------------------------------------------------------------
__device__ __forceinline__ void ln_wave(const float* ys, float* outp,
                                        const float* __restrict__ g,
                                        const float* __restrict__ bln, int l) {
  float a = ys[l];
  float bv = ys[l + 64];
  bool has3 = (l + 128) < HH;
  float cv = has3 ? ys[l + 128] : 0.0f;
  float s = a + bv + cv;
  #pragma unroll
  for (int m = 32; m; m >>= 1) s += __shfl_xor(s, m);
  float mu = s * (1.0f / HH);
  float da = a - mu, db = bv - mu, dc = has3 ? (cv - mu) : 0.0f;
  float s2 = da * da + db * db + dc * dc;
  #pragma unroll
  for (int m = 32; m; m >>= 1) s2 += __shfl_xor(s2, m);
  float rstd = rsqrtf(s2 * (1.0f / HH) + 1e-5f);
  outp[l]      = da * rstd * g[l] + bln[l];
  outp[l + 64] = db * rstd * g[l + 64] + bln[l + 64];
  if (has3) outp[l + 128] = dc * rstd * g[l + 128] + bln[l + 128];
}

// ---------------------------------------------------------------------------
// Kernel 4: y = attn_out @ W_fin + b_fin; x1 = LN(y+y)*g1+b1.  8 tokens/block.
// ---------------------------------------------------------------------------
__global__ __launch_bounds__(256) void k_fin_ln(
    const float* __restrict__ x, const float* __restrict__ W_fin,
    const float* __restrict__ b_fin, const float* __restrict__ g1,
    const float* __restrict__ b1ln, float* __restrict__ x1) {
  const int T = 8;
  int tok0 = blockIdx.x * T;
  int t = threadIdx.x;
  __shared__ float xs[T][HH];
  __shared__ float ys[T][HH];
  for (int idx = t; idx < T * HH; idx += 256)
    xs[idx / HH][idx % HH] = x[(size_t)tok0 * HH + idx];
  __syncthreads();
  for (int idx = t; idx < T * HH; idx += 256) {
    int tt = idx / HH, c = idx % HH;
    float acc = b_fin[c];
    #pragma unroll 4
    for (int cp = 0; cp < HH; ++cp) acc = fmaf(xs[tt][cp], W_fin[cp * HH + c], acc);
    ys[tt][c] = 2.0f * acc;
  }
  __syncthreads();
  int w = t >> 6, l = t & 63;
  #pragma unroll
  for (int k2 = 0; k2 < 2; ++k2) {
    int tt = w * 2 + k2;
    ln_wave(ys[tt], x1 + (size_t)(tok0 + tt) * HH, g1, b1ln, l);
  }
}

// ---------------------------------------------------------------------------
// Kernel 5: FFN + LN2.  h1 = relu(x1@W1+b1); y2 = h1@W2+b2; out = LN(y2+y2).
// 8 tokens/block.
// ---------------------------------------------------------------------------
__global__ __launch_bounds__(256) void k_ffn(
    const float* __restrict__ x1, const float* __restrict__ W1,
    const float* __restrict__ b1, const float* __restrict__ W2,
    const float* __restrict__ b2, const float* __restrict__ g2,
    const float* __restrict__ b2ln, float* __restrict__ out) {
  const int T = 8;
  int tok0 = blockIdx.x * T;
  int t = threadIdx.x;
  __shared__ float xs[T][HH];
  __shared__ float hs[T][FF_];
  __shared__ float ys[T][HH];
  for (int idx = t; idx < T * HH; idx += 256)
    xs[idx / HH][idx % HH] = x1[(size_t)tok0 * HH + idx];
  __syncthreads();
  for (int idx = t; idx < T * FF_; idx += 256) {
    int tt = idx / FF_, f = idx % FF_;
    float acc = b1[f];
    #pragma unroll 4
    for (int cp = 0; cp < HH; ++cp) acc = fmaf(xs[tt][cp], W1[(size_t)cp * FF_ + f], acc);
    hs[tt][f] = fmaxf(acc, 0.0f);
  }
  __syncthreads();
  for (int idx = t; idx < T * HH; idx += 256) {
    int tt = idx / HH, c = idx % HH;
    float acc = b2[c];
    #pragma unroll 4
    for (int f = 0; f < FF_; ++f) acc = fmaf(hs[tt][f], W2[(size_t)f * HH + c], acc);
    ys[tt][c] = 2.0f * acc;
  }
  __syncthreads();
  int w = t >> 6, l = t & 63;
  #pragma unroll
  for (int k2 = 0; k2 < 2; ++k2) {
    int tt = w * 2 + k2;
    ln_wave(ys[tt], out + (size_t)(tok0 + tt) * HH, g2, b2ln, l);
  }
}

// ---------------------------------------------------------------------------
extern "C" void kernel_launch(void* const* d_in, const int* in_sizes, int n_in,
                              void* d_out, int out_size, void* d_ws, size_t ws_size,
                              hipStream_t stream) {
  const float* inp    = (const float*)d_in[0];
  const int*   pos_s  = (const int*)d_in[1];
  const int*   pos_e  = (const int*)d_in[2];
  const int*   seq_ln = (const int*)d_in[3];
  const int*   lex_nm = (const int*)d_in[4];
  const float* pe_ss  = (const float*)d_in[5];
  const float* pe_se  = (const float*)d_in[6];
  const float* pe_es  = (const float*)d_in[7];
  const float* pe_ee  = (const float*)d_in[8];
  const float* W_fus  = (const float*)d_in[9];
  const float* b_fus  = (const float*)d_in[10];
  const float* Wq     = (const float*)d_in[11];
  const float* bq     = (const float*)d_in[12];
  const float* Wk     = (const float*)d_in[13];
  const float* bk     = (const float*)d_in[14];
  const float* Wv     = (const float*)d_in[15];
  const float* bv     = (const float*)d_in[16];
  const float* Wr     = (const float*)d_in[17];
  const float* br     = (const float*)d_in[18];
  const float* utab   = (const float*)d_in[19];
  const float* vtab   = (const float*)d_in[20];
  const float* W_fin  = (const float*)d_in[21];
  const float* b_fin  = (const float*)d_in[22];
  const float* ln1_g  = (const float*)d_in[23];
  const float* ln1_b  = (const float*)d_in[24];
  const float* W1     = (const float*)d_in[25];
  const float* b1     = (const float*)d_in[26];
  const float* W2     = (const float*)d_in[27];
  const float* b2     = (const float*)d_in[28];
  const float* ln2_g  = (const float*)d_in[29];
  const float* ln2_b  = (const float*)d_in[30];

  float* ws = (float*)d_ws;
  // workspace layout (floats)
  float* P        = ws;                       // 4*1025*160   = 656000
  float* qb       = P + 4 * TBL * HH;         // 163840
  float* kb       = qb + BB * SS * HH;        // 163840
  float* vb       = kb + BB * SS * HH;        // 163840
  float* gmat     = vb + BB * SS * HH;        // 4*256*8*160  = 1310720
  float* gbb      = gmat + (size_t)BB * SS * NH_ * HH;  // 8192
  float* attn_out = gbb + BB * SS * NH_;      // 163840
  float* x1       = attn_out + BB * SS * HH;  // 163840

  (void)in_sizes; (void)n_in; (void)out_size; (void)ws_size;

  k_ptab<<<dim3(TBL, 4), 160, 0, stream>>>(pe_ss, pe_se, pe_es, pe_ee, W_fus, b_fus, P);
  k_qkvg<<<BB * SS / 8, 256, 0, stream>>>(inp, Wq, bq, Wk, bk, Wv, bv, Wr, br, vtab,
                                          qb, kb, vb, gmat, gbb);
  k_attn<<<BB * SS, 256, 0, stream>>>(qb, kb, vb, gmat, gbb, P, pos_s, pos_e,
                                      seq_ln, lex_nm, utab, attn_out);
  k_fin_ln<<<BB * SS / 8, 256, 0, stream>>>(attn_out, W_fin, b_fin, ln1_g, ln1_b, x1);
  k_ffn<<<BB * SS / 8, 256, 0, stream>>>(x1, W1, b1, W2, b2, ln2_g, ln2_b, (float*)d_out);
}

// Round 2
// 252.583 us; speedup vs baseline: 2.2127x; 2.2127x over previous
//
#include <hip/hip_runtime.h>
#include <math.h>

// Problem constants
#define SS    256      // seq len
#define BB    4        // batch
#define HH    160      // hidden
#define NH_   8        // heads
#define HD_   20       // head dim
#define TBL   1025     // 2*MAXLEN+1
#define MAXL  512
#define FF_   640

// ---------------------------------------------------------------------------
// Kernel 1: P tables.  P[tab][row][c] = sum_cp pe_tab[row,cp] * W_fus[tab*H+cp, c]
// b_fus folded into tab 0.   grid (1025, 4), block 160
// ---------------------------------------------------------------------------
__global__ __launch_bounds__(160) void k_ptab(
    const float* __restrict__ pe_ss, const float* __restrict__ pe_se,
    const float* __restrict__ pe_es, const float* __restrict__ pe_ee,
    const float* __restrict__ W_fus, const float* __restrict__ b_fus,
    float* __restrict__ P) {
  int row = blockIdx.x, tab = blockIdx.y, c = threadIdx.x;
  const float* pe = (tab == 0) ? pe_ss : (tab == 1) ? pe_se : (tab == 2) ? pe_es : pe_ee;
  __shared__ __align__(16) float xs[HH];
  xs[c] = pe[row * HH + c];
  __syncthreads();
  float acc = (tab == 0) ? b_fus[c] : 0.0f;
  const float* wcol = W_fus + (size_t)tab * HH * HH + c;
  #pragma unroll 8
  for (int cp = 0; cp < HH; ++cp) acc = fmaf(xs[cp], wcol[cp * HH], acc);
  P[((size_t)tab * TBL + row) * HH + c] = acc;
}

// ---------------------------------------------------------------------------
// Generic tiled GEMM: C[M,N] = op(A[M,KK] @ W[KK,N] + bias)
// Block: TT tokens x 64 cols; 256 threads = 64 cols x 4 waves; each wave owns
// TT/4 tokens -> TT/4 accumulators per thread.  A-tile in LDS (broadcast
// reads, conflict-free).  W streamed coalesced, 16 independent loads in
// flight via unroll.
// grid: (M/TT, ceil(N/64))
// ---------------------------------------------------------------------------
template<int TT, int KK, bool RELU>
__global__ __launch_bounds__(256) void k_gemm(
    const float* __restrict__ A, const float* __restrict__ W,
    const float* __restrict__ bias, float* __restrict__ C, int N) {
  const int TPW = TT / 4;
  int tok0 = blockIdx.x * TT;
  int t = threadIdx.x;
  __shared__ __align__(16) float As[TT][KK];
  {
    const float4* src = (const float4*)(A + (size_t)tok0 * KK);
    float4* dst = (float4*)As;
    for (int idx = t; idx < TT * KK / 4; idx += 256) dst[idx] = src[idx];
  }
  __syncthreads();
  int c = (t & 63) + blockIdx.y * 64;
  int wv = t >> 6;
  if (c < N) {
    float acc[TPW];
    float bb = bias[c];
    #pragma unroll
    for (int i = 0; i < TPW; ++i) acc[i] = bb;
    const float* wp = W + c;
    #pragma unroll 4
    for (int k = 0; k < KK; k += 4) {
      float w0 = wp[(size_t)(k + 0) * N];
      float w1 = wp[(size_t)(k + 1) * N];
      float w2 = wp[(size_t)(k + 2) * N];
      float w3 = wp[(size_t)(k + 3) * N];
      #pragma unroll
      for (int i = 0; i < TPW; ++i) {
        const float4 a4 = *(const float4*)&As[wv * TPW + i][k];
        acc[i] = fmaf(a4.x, w0, acc[i]);
        acc[i] = fmaf(a4.y, w1, acc[i]);
        acc[i] = fmaf(a4.z, w2, acc[i]);
        acc[i] = fmaf(a4.w, w3, acc[i]);
      }
    }
    #pragma unroll
    for (int i = 0; i < TPW; ++i) {
      float v = RELU ? fmaxf(acc[i], 0.0f) : acc[i];
      C[(size_t)(tok0 + wv * TPW + i) * N + c] = v;
    }
  }
}

// ---------------------------------------------------------------------------
// Kernel 3: fused attention. One block per (b, i). 256 threads, thread = j.
// Startup: load q row; qu = q+u, qv = q+v; compute g[h][c] = sum_d qv[h,d]*Wr[c,h*20+d].
// (The br / gb term is constant over j -> cancels in softmax; dropped.)
// Main: rel[j,c] = relu(sum of 4 P gathers); bd[h] = sum_c rel*g; ac[h] = qu.k;
// mask -> softmax -> PV.
// ---------------------------------------------------------------------------
__global__ __launch_bounds__(256) void k_attn(
    const float* __restrict__ qb, const float* __restrict__ kb, const float* __restrict__ vb,
    const float* __restrict__ Wr, const float* __restrict__ P,
    const int* __restrict__ pos_s, const int* __restrict__ pos_e,
    const int* __restrict__ seq_len, const int* __restrict__ lex_num,
    const float* __restrict__ utab, const float* __restrict__ vtab,
    float* __restrict__ attn_out) {
  int blk = blockIdx.x;        // b*S + i
  int b = blk >> 8;
  int i = blk & 255;
  int t = threadIdx.x;         // j
  __shared__ __align__(16) float qu[HH];
  __shared__ __align__(16) float qv[HH];
  __shared__ __align__(16) float g_s[NH_ * HH];
  __shared__ __align__(16) float sc[NH_][SS];

  if (t < HH) {
    float q = qb[(size_t)blk * HH + t];
    qu[t] = q + utab[t];
    qv[t] = q + vtab[t];
  }
  __syncthreads();
  // g[h][cc] = sum_d qv[h*20+d] * Wr[cc*160 + h*20+d]  (1280 outputs, 5/thread)
  for (int p = t; p < NH_ * HH; p += 256) {
    int h = p / HH, cc = p - h * HH;
    const float4* wr4 = (const float4*)(Wr + (size_t)cc * HH + h * HD_);
    const float4* q4  = (const float4*)(qv + h * HD_);
    float acc = 0.0f;
    #pragma unroll
    for (int d4 = 0; d4 < HD_ / 4; ++d4) {
      float4 w4 = wr4[d4], qq = q4[d4];
      acc = fmaf(qq.x, w4.x, acc);
      acc = fmaf(qq.y, w4.y, acc);
      acc = fmaf(qq.z, w4.z, acc);
      acc = fmaf(qq.w, w4.w, acc);
    }
    g_s[p] = acc;
  }
  __syncthreads();

  int j = t;
  int psi = pos_s[b * SS + i], pei = pos_e[b * SS + i];
  int psj = pos_s[b * SS + j], pej = pos_e[b * SS + j];
  const float* r0 = P + (size_t)(psi - psj + MAXL) * HH;
  const float* r1 = P + ((size_t)TBL + (psi - pej + MAXL)) * HH;
  const float* r2 = P + ((size_t)2 * TBL + (pei - psj + MAXL)) * HH;
  const float* r3 = P + ((size_t)3 * TBL + (pei - pej + MAXL)) * HH;

  float bd[NH_];
  #pragma unroll
  for (int h = 0; h < NH_; ++h) bd[h] = 0.0f;

  #pragma unroll 2
  for (int cq = 0; cq < HH / 4; ++cq) {
    float4 a0 = *(const float4*)(r0 + cq * 4);
    float4 a1 = *(const float4*)(r1 + cq * 4);
    float4 a2 = *(const float4*)(r2 + cq * 4);
    float4 a3 = *(const float4*)(r3 + cq * 4);
    float rl0 = fmaxf(a0.x + a1.x + a2.x + a3.x, 0.0f);
    float rl1 = fmaxf(a0.y + a1.y + a2.y + a3.y, 0.0f);
    float rl2 = fmaxf(a0.z + a1.z + a2.z + a3.z, 0.0f);
    float rl3 = fmaxf(a0.w + a1.w + a2.w + a3.w, 0.0f);
    #pragma unroll
    for (int h = 0; h < NH_; ++h) {
      float4 gv = *(const float4*)(&g_s[h * HH + cq * 4]);
      bd[h] = fmaf(rl0, gv.x, bd[h]);
      bd[h] = fmaf(rl1, gv.y, bd[h]);
      bd[h] = fmaf(rl2, gv.z, bd[h]);
      bd[h] = fmaf(rl3, gv.w, bd[h]);
    }
  }

  // A_C
  float ac[NH_];
  const float* krow = kb + (size_t)(b * SS + j) * HH;
  #pragma unroll
  for (int h = 0; h < NH_; ++h) {
    const float4* k4 = (const float4*)(krow + h * HD_);
    const float4* q4 = (const float4*)(&qu[h * HD_]);
    float acc = 0.0f;
    #pragma unroll
    for (int d4 = 0; d4 < HD_ / 4; ++d4) {
      float4 kv = k4[d4]; float4 qvv = q4[d4];
      acc = fmaf(qvv.x, kv.x, acc);
      acc = fmaf(qvv.y, kv.y, acc);
      acc = fmaf(qvv.z, kv.z, acc);
      acc = fmaf(qvv.w, kv.w, acc);
    }
    ac[h] = acc;
  }

  int limit = seq_len[b] + lex_num[0];
  const float scale = 0.22360679774997896f;  // 1/sqrt(20)
  bool valid = (j < limit);
  #pragma unroll
  for (int h = 0; h < NH_; ++h)
    sc[h][j] = valid ? (ac[h] + bd[h]) * scale : -1.0e15f;
  __syncthreads();

  // softmax: 8 groups of 32 lanes; group handles one head
  {
    int h = t >> 5, l = t & 31;
    float m = -3.0e38f;
    float e[8];
    #pragma unroll
    for (int ii = 0; ii < 8; ++ii) m = fmaxf(m, sc[h][l + ii * 32]);
    #pragma unroll
    for (int msk = 16; msk; msk >>= 1) m = fmaxf(m, __shfl_xor(m, msk));
    float s = 0.0f;
    #pragma unroll
    for (int ii = 0; ii < 8; ++ii) { e[ii] = __expf(sc[h][l + ii * 32] - m); s += e[ii]; }
    #pragma unroll
    for (int msk = 16; msk; msk >>= 1) s += __shfl_xor(s, msk);
    float inv = 1.0f / s;
    #pragma unroll
    for (int ii = 0; ii < 8; ++ii) sc[h][l + ii * 32] = e[ii] * inv;
  }
  __syncthreads();

  // PV: thread c<160 computes out[c]; h = c/20
  if (t < HH) {
    int h = t / HD_;
    float acc0 = 0.f, acc1 = 0.f, acc2 = 0.f, acc3 = 0.f;
    const float* vcol = vb + (size_t)b * SS * HH + t;
    #pragma unroll 2
    for (int j2 = 0; j2 < SS; j2 += 4) {
      acc0 = fmaf(sc[h][j2 + 0], vcol[(size_t)(j2 + 0) * HH], acc0);
      acc1 = fmaf(sc[h][j2 + 1], vcol[(size_t)(j2 + 1) * HH], acc1);
      acc2 = fmaf(sc[h][j2 + 2], vcol[(size_t)(j2 + 2) * HH], acc2);
      acc3 = fmaf(sc[h][j2 + 3], vcol[(size_t)(j2 + 3) * HH], acc3);
    }
    attn_out[(size_t)blk * HH + t] = (acc0 + acc1) + (acc2 + acc3);
  }
}

// ---------------------------------------------------------------------------
// LayerNorm over rows of 160.  LN(y+y) == LN(y) with eps/4.
// grid 256 blocks x 256 threads; wave per token.
// ---------------------------------------------------------------------------
__global__ __launch_bounds__(256) void k_ln(
    const float* __restrict__ Y, const float* __restrict__ g,
    const float* __restrict__ bln, float* __restrict__ O) {
  int tok = blockIdx.x * 4 + (threadIdx.x >> 6);
  int l = threadIdx.x & 63;
  const float* y = Y + (size_t)tok * HH;
  float a = y[l];
  float bv = y[l + 64];
  bool has3 = l < (HH - 128);
  float cv = has3 ? y[l + 128] : 0.0f;
  float s = a + bv + cv;
  #pragma unroll
  for (int m = 32; m; m >>= 1) s += __shfl_xor(s, m);
  float mu = s * (1.0f / HH);
  float da = a - mu, db = bv - mu, dc = has3 ? (cv - mu) : 0.0f;
  float s2 = da * da + db * db + dc * dc;
  #pragma unroll
  for (int m = 32; m; m >>= 1) s2 += __shfl_xor(s2, m);
  float rstd = rsqrtf(s2 * (1.0f / HH) + 2.5e-6f);  // eps 1e-5 / 4
  float* o = O + (size_t)tok * HH;
  o[l]      = da * rstd * g[l] + bln[l];
  o[l + 64] = db * rstd * g[l + 64] + bln[l + 64];
  if (has3) o[l + 128] = dc * rstd * g[l + 128] + bln[l + 128];
}

// ---------------------------------------------------------------------------
extern "C" void kernel_launch(void* const* d_in, const int* in_sizes, int n_in,
                              void* d_out, int out_size, void* d_ws, size_t ws_size,
                              hipStream_t stream) {
  const float* inp    = (const float*)d_in[0];
  const int*   pos_s  = (const int*)d_in[1];
  const int*   pos_e  = (const int*)d_in[2];
  const int*   seq_ln = (const int*)d_in[3];
  const int*   lex_nm = (const int*)d_in[4];
  const float* pe_ss  = (const float*)d_in[5];
  const float* pe_se  = (const float*)d_in[6];
  const float* pe_es  = (const float*)d_in[7];
  const float* pe_ee  = (const float*)d_in[8];
  const float* W_fus  = (const float*)d_in[9];
  const float* b_fus  = (const float*)d_in[10];
  const float* Wq     = (const float*)d_in[11];
  const float* bq     = (const float*)d_in[12];
  const float* Wk     = (const float*)d_in[13];
  const float* bk     = (const float*)d_in[14];
  const float* Wv     = (const float*)d_in[15];
  const float* bv     = (const float*)d_in[16];
  const float* Wr     = (const float*)d_in[17];
  // d_in[18] = br  -- constant-over-j term, cancels in softmax; unused
  const float* utab   = (const float*)d_in[19];
  const float* vtab   = (const float*)d_in[20];
  const float* W_fin  = (const float*)d_in[21];
  const float* b_fin  = (const float*)d_in[22];
  const float* ln1_g  = (const float*)d_in[23];
  const float* ln1_b  = (const float*)d_in[24];
  const float* W1     = (const float*)d_in[25];
  const float* b1     = (const float*)d_in[26];
  const float* W2     = (const float*)d_in[27];
  const float* b2     = (const float*)d_in[28];
  const float* ln2_g  = (const float*)d_in[29];
  const float* ln2_b  = (const float*)d_in[30];

  float* ws = (float*)d_ws;
  // workspace layout (floats)
  float* P        = ws;                        // 4*1025*160 = 656000
  float* qb       = P + 4 * TBL * HH;          // 163840
  float* kb       = qb + BB * SS * HH;
  float* vb       = kb + BB * SS * HH;
  float* attn_out = vb + BB * SS * HH;
  float* ybuf     = attn_out + BB * SS * HH;
  float* x1       = ybuf + BB * SS * HH;
  float* hbuf     = x1 + BB * SS * HH;         // 1024*640 = 655360
  float* y2       = hbuf + (size_t)BB * SS * FF_;

  (void)in_sizes; (void)n_in; (void)out_size; (void)ws_size;

  const int M = BB * SS;  // 1024

  k_ptab<<<dim3(TBL, 4), 160, 0, stream>>>(pe_ss, pe_se, pe_es, pe_ee, W_fus, b_fus, P);
  k_gemm<16, HH, false><<<dim3(M / 16, 3), 256, 0, stream>>>(inp, Wq, bq, qb, HH);
  k_gemm<16, HH, false><<<dim3(M / 16, 3), 256, 0, stream>>>(inp, Wk, bk, kb, HH);
  k_gemm<16, HH, false><<<dim3(M / 16, 3), 256, 0, stream>>>(inp, Wv, bv, vb, HH);
  k_attn<<<M, 256, 0, stream>>>(qb, kb, vb, Wr, P, pos_s, pos_e, seq_ln, lex_nm,
                                utab, vtab, attn_out);
  k_gemm<8, HH, false><<<dim3(M / 8, 3), 256, 0, stream>>>(attn_out, W_fin, b_fin, ybuf, HH);
  k_ln<<<M / 4, 256, 0, stream>>>(ybuf, ln1_g, ln1_b, x1);
  k_gemm<16, HH, true><<<dim3(M / 16, 10), 256, 0, stream>>>(x1, W1, b1, hbuf, FF_);
  k_gemm<8, FF_, false><<<dim3(M / 8, 3), 256, 0, stream>>>(hbuf, W2, b2, y2, HH);
  k_ln<<<M / 4, 256, 0, stream>>>(y2, ln2_g, ln2_b, (float*)d_out);
}

// Round 3
// 218.582 us; speedup vs baseline: 2.5569x; 1.1556x over previous
//
#include <hip/hip_runtime.h>
#include <math.h>

// Problem constants
#define SS    256      // seq len
#define BB    4        // batch
#define HH    160      // hidden
#define NH_   8        // heads
#define HD_   20       // head dim
#define TBL   1025     // 2*MAXLEN+1
#define MAXL  512
#define FF_   640

// ---------------------------------------------------------------------------
// Kernel 1: P tables.  P[tab][row][c] = sum_cp pe_tab[row,cp] * W_fus[tab*H+cp, c]
// b_fus folded into tab 0.   grid (1025, 4), block 160
// ---------------------------------------------------------------------------
__global__ __launch_bounds__(160) void k_ptab(
    const float* __restrict__ pe_ss, const float* __restrict__ pe_se,
    const float* __restrict__ pe_es, const float* __restrict__ pe_ee,
    const float* __restrict__ W_fus, const float* __restrict__ b_fus,
    float* __restrict__ P) {
  int row = blockIdx.x, tab = blockIdx.y, c = threadIdx.x;
  const float* pe = (tab == 0) ? pe_ss : (tab == 1) ? pe_se : (tab == 2) ? pe_es : pe_ee;
  __shared__ __align__(16) float xs[HH];
  xs[c] = pe[row * HH + c];
  __syncthreads();
  float acc = (tab == 0) ? b_fus[c] : 0.0f;
  const float* wcol = W_fus + (size_t)tab * HH * HH + c;
  #pragma unroll 8
  for (int cp = 0; cp < HH; ++cp) acc = fmaf(xs[cp], wcol[cp * HH], acc);
  P[((size_t)tab * TBL + row) * HH + c] = acc;
}

// ---------------------------------------------------------------------------
// Generic tiled GEMM: C[M,N] = op(A[M,KK] @ W[KK,N] + bias)
// Block: TT tokens x 64 cols; 256 threads = 64 cols x 4 waves; wave owns TT/4
// tokens.  A-tile in LDS (wave-uniform broadcast reads).  W streamed
// coalesced, 8 loads in flight.
// ---------------------------------------------------------------------------
template<int TT, int KK, bool RELU>
__global__ __launch_bounds__(256) void k_gemm(
    const float* __restrict__ A, const float* __restrict__ W,
    const float* __restrict__ bias, float* __restrict__ C, int N) {
  const int TPW = TT / 4;
  int tok0 = blockIdx.x * TT;
  int t = threadIdx.x;
  __shared__ __align__(16) float As[TT][KK];
  {
    const float4* src = (const float4*)(A + (size_t)tok0 * KK);
    float4* dst = (float4*)As;
    for (int idx = t; idx < TT * KK / 4; idx += 256) dst[idx] = src[idx];
  }
  __syncthreads();
  int c = (t & 63) + blockIdx.y * 64;
  int wv = t >> 6;
  if (c < N) {
    float acc[TPW];
    float bb = bias[c];
    #pragma unroll
    for (int i = 0; i < TPW; ++i) acc[i] = bb;
    const float* wp = W + c;
    #pragma unroll 2
    for (int k = 0; k < KK; k += 8) {
      float w[8];
      #pragma unroll
      for (int q = 0; q < 8; ++q) w[q] = wp[(size_t)(k + q) * N];
      #pragma unroll
      for (int i = 0; i < TPW; ++i) {
        const float4 a0 = *(const float4*)&As[wv * TPW + i][k];
        const float4 a1 = *(const float4*)&As[wv * TPW + i][k + 4];
        acc[i] = fmaf(a0.x, w[0], acc[i]);
        acc[i] = fmaf(a0.y, w[1], acc[i]);
        acc[i] = fmaf(a0.z, w[2], acc[i]);
        acc[i] = fmaf(a0.w, w[3], acc[i]);
        acc[i] = fmaf(a1.x, w[4], acc[i]);
        acc[i] = fmaf(a1.y, w[5], acc[i]);
        acc[i] = fmaf(a1.z, w[6], acc[i]);
        acc[i] = fmaf(a1.w, w[7], acc[i]);
      }
    }
    #pragma unroll
    for (int i = 0; i < TPW; ++i) {
      float v = RELU ? fmaxf(acc[i], 0.0f) : acc[i];
      C[(size_t)(tok0 + wv * TPW + i) * N + c] = v;
    }
  }
}

// ---------------------------------------------------------------------------
// Fused Q/K/V projection: one launch, grid (M/16, 8); cols 0..479 map to
// (Wq|Wk|Wv) column space; 480..511 idle.
// ---------------------------------------------------------------------------
__global__ __launch_bounds__(256) void k_qkv(
    const float* __restrict__ A,
    const float* __restrict__ Wq, const float* __restrict__ bq,
    const float* __restrict__ Wk, const float* __restrict__ bk,
    const float* __restrict__ Wv, const float* __restrict__ bv,
    float* __restrict__ qb, float* __restrict__ kb, float* __restrict__ vb) {
  const int TT = 16, TPW = 4;
  int tok0 = blockIdx.x * TT;
  int t = threadIdx.x;
  __shared__ __align__(16) float As[TT][HH];
  {
    const float4* src = (const float4*)(A + (size_t)tok0 * HH);
    float4* dst = (float4*)As;
    for (int idx = t; idx < TT * HH / 4; idx += 256) dst[idx] = src[idx];
  }
  __syncthreads();
  int col = (t & 63) + blockIdx.y * 64;   // 0..511
  int wv = t >> 6;
  if (col < 480) {
    int mat = col / 160;
    int c = col - mat * 160;
    const float* W   = (mat == 0) ? Wq : (mat == 1) ? Wk : Wv;
    const float* bia = (mat == 0) ? bq : (mat == 1) ? bk : bv;
    float* O         = (mat == 0) ? qb : (mat == 1) ? kb : vb;
    float acc[TPW];
    float bb = bia[c];
    #pragma unroll
    for (int i = 0; i < TPW; ++i) acc[i] = bb;
    const float* wp = W + c;
    #pragma unroll 2
    for (int k = 0; k < HH; k += 8) {
      float w[8];
      #pragma unroll
      for (int q = 0; q < 8; ++q) w[q] = wp[(size_t)(k + q) * HH];
      #pragma unroll
      for (int i = 0; i < TPW; ++i) {
        const float4 a0 = *(const float4*)&As[wv * TPW + i][k];
        const float4 a1 = *(const float4*)&As[wv * TPW + i][k + 4];
        acc[i] = fmaf(a0.x, w[0], acc[i]);
        acc[i] = fmaf(a0.y, w[1], acc[i]);
        acc[i] = fmaf(a0.z, w[2], acc[i]);
        acc[i] = fmaf(a0.w, w[3], acc[i]);
        acc[i] = fmaf(a1.x, w[4], acc[i]);
        acc[i] = fmaf(a1.y, w[5], acc[i]);
        acc[i] = fmaf(a1.z, w[6], acc[i]);
        acc[i] = fmaf(a1.w, w[7], acc[i]);
      }
    }
    #pragma unroll
    for (int i = 0; i < TPW; ++i)
      O[(size_t)(tok0 + wv * TPW + i) * HH + c] = acc[i];
  }
}

// ---------------------------------------------------------------------------
// Kernel 3: fused attention, coalesced P access. One block per (b, i).
// Per j-tile of 32: stage1 cooperatively streams the 4x32 P rows (coalesced
// float4), sums+relu into rel_s; stage2 contracts rel_s x g_s (broadcast LDS
// reads, conflict-free) into bd scores.  Then A_C, mask, softmax, PV.
// (br/gb term is constant over j -> cancels in softmax; dropped.)
// ---------------------------------------------------------------------------
#define JT 32
#define RSTR 164   // rel_s/g_s row stride (16B aligned, pads banks)

__global__ __launch_bounds__(256) void k_attn(
    const float* __restrict__ qb, const float* __restrict__ kb, const float* __restrict__ vb,
    const float* __restrict__ Wr, const float* __restrict__ P,
    const int* __restrict__ pos_s, const int* __restrict__ pos_e,
    const int* __restrict__ seq_len, const int* __restrict__ lex_num,
    const float* __restrict__ utab, const float* __restrict__ vtab,
    float* __restrict__ attn_out) {
  int blk = blockIdx.x;        // b*S + i
  int b = blk >> 8;
  int i = blk & 255;
  int t = threadIdx.x;
  __shared__ __align__(16) float qu[HH];
  __shared__ __align__(16) float qv[HH];
  __shared__ __align__(16) float g_s[NH_][RSTR];
  __shared__ __align__(16) float rel_s[JT][RSTR];
  __shared__ __align__(16) float sc[NH_][SS];
  __shared__ int ps_s[SS], pe_s[SS];

  if (t < HH) {
    float q = qb[(size_t)blk * HH + t];
    qu[t] = q + utab[t];
    qv[t] = q + vtab[t];
  }
  ps_s[t] = pos_s[b * SS + t];
  pe_s[t] = pos_e[b * SS + t];
  __syncthreads();

  // g[h][cc] = sum_d qv[h*20+d] * Wr[cc*160 + h*20+d]   (1280 outputs)
  for (int p = t; p < NH_ * HH; p += 256) {
    int h = p / HH, cc = p - h * HH;
    const float4* wr4 = (const float4*)(Wr + (size_t)cc * HH + h * HD_);
    const float4* q4  = (const float4*)(qv + h * HD_);
    float acc = 0.0f;
    #pragma unroll
    for (int d4 = 0; d4 < HD_ / 4; ++d4) {
      float4 w4 = wr4[d4], qq = q4[d4];
      acc = fmaf(qq.x, w4.x, acc);
      acc = fmaf(qq.y, w4.y, acc);
      acc = fmaf(qq.z, w4.z, acc);
      acc = fmaf(qq.w, w4.w, acc);
    }
    g_s[h][cc] = acc;
  }
  __syncthreads();

  int psi = ps_s[i], pei = pe_s[i];
  const float* P0 = P;
  const float* P1 = P + (size_t)TBL * HH;
  const float* P2 = P + (size_t)2 * TBL * HH;
  const float* P3 = P + (size_t)3 * TBL * HH;

  for (int tl = 0; tl < SS / JT; ++tl) {
    // ---- stage 1: coalesced row streaming.  JT*HH/4 = 1280 float4s, 5/thread
    #pragma unroll
    for (int r = 0; r < JT * HH / 4 / 256; ++r) {
      int idx4 = r * 256 + t;
      int jj = idx4 / (HH / 4);          // /40
      int c4 = idx4 - jj * (HH / 4);
      int j = tl * JT + jj;
      int psj = ps_s[j], pej = pe_s[j];
      float4 a0 = *(const float4*)(P0 + (size_t)(psi - psj + MAXL) * HH + c4 * 4);
      float4 a1 = *(const float4*)(P1 + (size_t)(psi - pej + MAXL) * HH + c4 * 4);
      float4 a2 = *(const float4*)(P2 + (size_t)(pei - psj + MAXL) * HH + c4 * 4);
      float4 a3 = *(const float4*)(P3 + (size_t)(pei - pej + MAXL) * HH + c4 * 4);
      float4 rl;
      rl.x = fmaxf(a0.x + a1.x + a2.x + a3.x, 0.0f);
      rl.y = fmaxf(a0.y + a1.y + a2.y + a3.y, 0.0f);
      rl.z = fmaxf(a0.z + a1.z + a2.z + a3.z, 0.0f);
      rl.w = fmaxf(a0.w + a1.w + a2.w + a3.w, 0.0f);
      *(float4*)&rel_s[jj][c4 * 4] = rl;
    }
    __syncthreads();
    // ---- stage 2: bd[h][jj] = sum_c rel_s[jj][c] * g_s[h][c]
    {
      int h = t & 7, jj = t >> 3;        // 8 addrs per wave each -> broadcast
      float acc = 0.0f;
      #pragma unroll 8
      for (int c4 = 0; c4 < HH / 4; ++c4) {
        float4 rv = *(const float4*)&rel_s[jj][c4 * 4];
        float4 gv = *(const float4*)&g_s[h][c4 * 4];
        acc = fmaf(rv.x, gv.x, acc);
        acc = fmaf(rv.y, gv.y, acc);
        acc = fmaf(rv.z, gv.z, acc);
        acc = fmaf(rv.w, gv.w, acc);
      }
      sc[h][tl * JT + jj] = acc;
    }
    __syncthreads();
  }

  // ---- A_C + mask + combine
  {
    int j = t;
    float ac[NH_];
    const float* krow = kb + (size_t)(b * SS + j) * HH;
    #pragma unroll
    for (int h = 0; h < NH_; ++h) {
      const float4* k4 = (const float4*)(krow + h * HD_);
      const float4* q4 = (const float4*)(&qu[h * HD_]);
      float acc = 0.0f;
      #pragma unroll
      for (int d4 = 0; d4 < HD_ / 4; ++d4) {
        float4 kv = k4[d4]; float4 qq = q4[d4];
        acc = fmaf(qq.x, kv.x, acc);
        acc = fmaf(qq.y, kv.y, acc);
        acc = fmaf(qq.z, kv.z, acc);
        acc = fmaf(qq.w, kv.w, acc);
      }
      ac[h] = acc;
    }
    int limit = seq_len[b] + lex_num[0];
    const float scale = 0.22360679774997896f;  // 1/sqrt(20)
    bool valid = (j < limit);
    #pragma unroll
    for (int h = 0; h < NH_; ++h)
      sc[h][j] = valid ? (ac[h] + sc[h][j]) * scale : -1.0e15f;
  }
  __syncthreads();

  // ---- softmax: 8 groups of 32 lanes, one head each
  {
    int h = t >> 5, l = t & 31;
    float m = -3.0e38f;
    float e[8];
    #pragma unroll
    for (int ii = 0; ii < 8; ++ii) m = fmaxf(m, sc[h][l + ii * 32]);
    #pragma unroll
    for (int msk = 16; msk; msk >>= 1) m = fmaxf(m, __shfl_xor(m, msk));
    float s = 0.0f;
    #pragma unroll
    for (int ii = 0; ii < 8; ++ii) { e[ii] = __expf(sc[h][l + ii * 32] - m); s += e[ii]; }
    #pragma unroll
    for (int msk = 16; msk; msk >>= 1) s += __shfl_xor(s, msk);
    float inv = 1.0f / s;
    #pragma unroll
    for (int ii = 0; ii < 8; ++ii) sc[h][l + ii * 32] = e[ii] * inv;
  }
  __syncthreads();

  // ---- PV: thread c<160 computes out[c]
  if (t < HH) {
    int h = t / HD_;
    float acc0 = 0.f, acc1 = 0.f, acc2 = 0.f, acc3 = 0.f;
    const float* vcol = vb + (size_t)b * SS * HH + t;
    #pragma unroll 2
    for (int j2 = 0; j2 < SS; j2 += 4) {
      acc0 = fmaf(sc[h][j2 + 0], vcol[(size_t)(j2 + 0) * HH], acc0);
      acc1 = fmaf(sc[h][j2 + 1], vcol[(size_t)(j2 + 1) * HH], acc1);
      acc2 = fmaf(sc[h][j2 + 2], vcol[(size_t)(j2 + 2) * HH], acc2);
      acc3 = fmaf(sc[h][j2 + 3], vcol[(size_t)(j2 + 3) * HH], acc3);
    }
    attn_out[(size_t)blk * HH + t] = (acc0 + acc1) + (acc2 + acc3);
  }
}

// ---------------------------------------------------------------------------
// LayerNorm over rows of 160.  LN(y+y) == LN(y) with eps/4.
// ---------------------------------------------------------------------------
__global__ __launch_bounds__(256) void k_ln(
    const float* __restrict__ Y, const float* __restrict__ g,
    const float* __restrict__ bln, float* __restrict__ O) {
  int tok = blockIdx.x * 4 + (threadIdx.x >> 6);
  int l = threadIdx.x & 63;
  const float* y = Y + (size_t)tok * HH;
  float a = y[l];
  float bv = y[l + 64];
  bool has3 = l < (HH - 128);
  float cv = has3 ? y[l + 128] : 0.0f;
  float s = a + bv + cv;
  #pragma unroll
  for (int m = 32; m; m >>= 1) s += __shfl_xor(s, m);
  float mu = s * (1.0f / HH);
  float da = a - mu, db = bv - mu, dc = has3 ? (cv - mu) : 0.0f;
  float s2 = da * da + db * db + dc * dc;
  #pragma unroll
  for (int m = 32; m; m >>= 1) s2 += __shfl_xor(s2, m);
  float rstd = rsqrtf(s2 * (1.0f / HH) + 2.5e-6f);  // eps 1e-5 / 4
  float* o = O + (size_t)tok * HH;
  o[l]      = da * rstd * g[l] + bln[l];
  o[l + 64] = db * rstd * g[l + 64] + bln[l + 64];
  if (has3) o[l + 128] = dc * rstd * g[l + 128] + bln[l + 128];
}

// ---------------------------------------------------------------------------
extern "C" void kernel_launch(void* const* d_in, const int* in_sizes, int n_in,
                              void* d_out, int out_size, void* d_ws, size_t ws_size,
                              hipStream_t stream) {
  const float* inp    = (const float*)d_in[0];
  const int*   pos_s  = (const int*)d_in[1];
  const int*   pos_e  = (const int*)d_in[2];
  const int*   seq_ln = (const int*)d_in[3];
  const int*   lex_nm = (const int*)d_in[4];
  const float* pe_ss  = (const float*)d_in[5];
  const float* pe_se  = (const float*)d_in[6];
  const float* pe_es  = (const float*)d_in[7];
  const float* pe_ee  = (const float*)d_in[8];
  const float* W_fus  = (const float*)d_in[9];
  const float* b_fus  = (const float*)d_in[10];
  const float* Wq     = (const float*)d_in[11];
  const float* bq     = (const float*)d_in[12];
  const float* Wk     = (const float*)d_in[13];
  const float* bk     = (const float*)d_in[14];
  const float* Wv     = (const float*)d_in[15];
  const float* bv     = (const float*)d_in[16];
  const float* Wr     = (const float*)d_in[17];
  // d_in[18] = br : constant-over-j term, cancels in softmax
  const float* utab   = (const float*)d_in[19];
  const float* vtab   = (const float*)d_in[20];
  const float* W_fin  = (const float*)d_in[21];
  const float* b_fin  = (const float*)d_in[22];
  const float* ln1_g  = (const float*)d_in[23];
  const float* ln1_b  = (const float*)d_in[24];
  const float* W1     = (const float*)d_in[25];
  const float* b1     = (const float*)d_in[26];
  const float* W2     = (const float*)d_in[27];
  const float* b2     = (const float*)d_in[28];
  const float* ln2_g  = (const float*)d_in[29];
  const float* ln2_b  = (const float*)d_in[30];

  float* ws = (float*)d_ws;
  float* P        = ws;                        // 4*1025*160 = 656000
  float* qb       = P + 4 * TBL * HH;
  float* kb       = qb + BB * SS * HH;
  float* vb       = kb + BB * SS * HH;
  float* attn_out = vb + BB * SS * HH;
  float* ybuf     = attn_out + BB * SS * HH;
  float* x1       = ybuf + BB * SS * HH;
  float* hbuf     = x1 + BB * SS * HH;         // 1024*640
  float* y2       = hbuf + (size_t)BB * SS * FF_;

  (void)in_sizes; (void)n_in; (void)out_size; (void)ws_size;

  const int M = BB * SS;  // 1024

  k_ptab<<<dim3(TBL, 4), 160, 0, stream>>>(pe_ss, pe_se, pe_es, pe_ee, W_fus, b_fus, P);
  k_qkv<<<dim3(M / 16, 8), 256, 0, stream>>>(inp, Wq, bq, Wk, bk, Wv, bv, qb, kb, vb);
  k_attn<<<M, 256, 0, stream>>>(qb, kb, vb, Wr, P, pos_s, pos_e, seq_ln, lex_nm,
                                utab, vtab, attn_out);
  k_gemm<8, HH, false><<<dim3(M / 8, 3), 256, 0, stream>>>(attn_out, W_fin, b_fin, ybuf, HH);
  k_ln<<<M / 4, 256, 0, stream>>>(ybuf, ln1_g, ln1_b, x1);
  k_gemm<16, HH, true><<<dim3(M / 16, 10), 256, 0, stream>>>(x1, W1, b1, hbuf, FF_);
  k_gemm<8, FF_, false><<<dim3(M / 8, 3), 256, 0, stream>>>(hbuf, W2, b2, y2, HH);
  k_ln<<<M / 4, 256, 0, stream>>>(y2, ln2_g, ln2_b, (float*)d_out);
}